// Round 8
// baseline (267.807 us; speedup 1.0000x reference)
//
#include <hip/hip_runtime.h>
#include <cstdint>
#include <cstddef>

#define N_  32
#define C_  64
#define T_  256
#define V_  25
#define R_  8
#define O_  64
#define K_  5
#define NU_ 17
#define U_  25
#define CV  (C_ * V_)        // 1600
#define KC  32               // K-chunk = 1 MFMA k-step
#define NCH (CV / KC)        // 50 chunks
#define OG  4                // o's per block
#define NB  (OG * 32)        // 128 ncols

#define OUT_ELEMS ((size_t)N_ * O_ * T_ * V_)   // 13,107,200

typedef __attribute__((ext_vector_type(8))) short bf16x8;
typedef __attribute__((ext_vector_type(4))) float f32x4;

// round-to-nearest-away, 2 ops
static __device__ __forceinline__ unsigned short f2bf(float f) {
    union { float f; unsigned u; } c; c.f = f;
    return (unsigned short)((c.u + 0x8000u) >> 16);
}
static __device__ __forceinline__ float bf2f(unsigned short h) {
    union { unsigned u; float f; } c; c.u = ((unsigned)h) << 16; return c.f;
}
static __device__ __forceinline__ unsigned pk2(float a, float b) {
    union { float f; unsigned u; } ca, cb; ca.f = a; cb.f = b;
    return ((ca.u + 0x8000u) >> 16) | ((cb.u + 0x8000u) & 0xFFFF0000u);
}

// ---------------------------------------------------------------------------
// k_xcast: fragment-native xT3 with cv' = v*64+c ordering:
//   xT3[n][tt(16)][s'(200)][tl(16)][ke(8)],  s' = v*8 + c/8, ke = c&7.
// Vectorized float4 input pass; flat per-c tile [c][t*25+v].
// Also per-t-block partial pool sums pp[n][tb][c*25+v].
// ---------------------------------------------------------------------------
__global__ void k_xcast(const float* __restrict__ x, unsigned short* __restrict__ xT3,
                        float* __restrict__ pp) {
    __shared__ unsigned short tile[C_][408];   // [c][t*25+v], row 816 B
    int bid = blockIdx.x;
    int n = bid >> 4, tb = bid & 15;
    int tid = threadIdx.x;
    // phase 1: 6400 float4 reads (coalesced), bf16-pack, 8B LDS writes
    const float* xb = x + (size_t)n * C_ * T_ * V_ + tb * 400;
#pragma unroll
    for (int it = 0; it < 25; ++it) {
        int i = it * 256 + tid;          // < 6400
        int c = i / 100, q = i - c * 100;
        float4 v4 = *(const float4*)(xb + (size_t)c * (T_ * V_) + q * 4);
        uint2 w;
        w.x = pk2(v4.x, v4.y);
        w.y = pk2(v4.z, v4.w);
        *(uint2*)&tile[c][q * 4] = w;
    }
    __syncthreads();
    // phase 2: write fragment tiles: dst = ((n*16+tb)*200 + s')*128 + tl*8
    unsigned short* dstb = xT3 + ((size_t)(n * 16 + tb) * 200) * 128;
    for (int i = tid; i < 200 * 16; i += 256) {
        int sp = i >> 4, tl = i & 15;
        int v = sp >> 3, c0 = (sp & 7) * 8;
        unsigned short h[8];
#pragma unroll
        for (int j = 0; j < 8; ++j) h[j] = tile[c0 + j][tl * 25 + v];
        uint4 pk;
        pk.x = (unsigned)h[0] | ((unsigned)h[1] << 16);
        pk.y = (unsigned)h[2] | ((unsigned)h[3] << 16);
        pk.z = (unsigned)h[4] | ((unsigned)h[5] << 16);
        pk.w = (unsigned)h[6] | ((unsigned)h[7] << 16);
        *(uint4*)(dstb + (size_t)sp * 128 + tl * 8) = pk;
    }
    // phase 3: partial pool
    float* ppd = pp + ((size_t)n * 16 + tb) * CV;
    for (int e = tid; e < CV; e += 256) {
        int c = e / 25, v = e - c * 25;
        float s = 0.f;
#pragma unroll
        for (int t = 0; t < 16; ++t) s += bf2f(tile[c][t * 25 + v]);
        ppd[e] = s;
    }
}

// classic pool (slow tier)
__global__ void k_pool(const float* __restrict__ x, float* __restrict__ pool) {
    int nc = blockIdx.x;
    int t  = threadIdx.x;
    const float* px = x + ((size_t)nc * T_ + t) * V_;
    float acc[V_];
#pragma unroll
    for (int v = 0; v < V_; ++v) acc[v] = px[v];
#pragma unroll
    for (int off = 32; off > 0; off >>= 1) {
#pragma unroll
        for (int v = 0; v < V_; ++v) acc[v] += __shfl_down(acc[v], off, 64);
    }
    __shared__ float sm[4][V_];
    int wave = t >> 6, lane = t & 63;
    if (lane == 0) {
#pragma unroll
        for (int v = 0; v < V_; ++v) sm[wave][v] = acc[v];
    }
    __syncthreads();
    if (t < V_) {
        float s = sm[0][t] + sm[1][t] + sm[2][t] + sm[3][t];
        pool[(size_t)nc * V_ + t] = s * (1.0f / T_);
    }
}

// ---------------------------------------------------------------------------
// k_tvals (slow tier only)
// ---------------------------------------------------------------------------
__global__ void k_tvals(const float* __restrict__ pool,
                        const float* __restrict__ W11, const float* __restrict__ b11,
                        const float* __restrict__ W12, const float* __restrict__ b12,
                        const float* __restrict__ W2,  const float* __restrict__ b2,
                        float* __restrict__ t2o, float* __restrict__ tSo) {
    int kn = blockIdx.x;
    int k = kn / N_, n = kn % N_;
    int tid = threadIdx.x;
    int r = tid >> 5, v = tid & 31;
    if (v >= V_) return;
    const float* pp = pool + (size_t)n * C_ * V_ + v;
    const float* w2 = W2 + ((size_t)k * R_ + r) * C_;
    const float* w1 = ((v < NU_) ? W11 : W12) + ((size_t)k * R_ + r) * C_;
    float a2 = b2[k * R_ + r];
    float a1 = (v < NU_) ? b11[k * R_ + r] : b12[k * R_ + r];
    for (int c = 0; c < C_; ++c) {
        float p = pp[(size_t)c * V_];
        a2 += w2[c] * p;
        a1 += w1[c] * p;
    }
    size_t idx = (((size_t)k * N_ + n) * R_ + r) * V_ + v;
    t2o[idx] = a2;
    tSo[idx] = a1;
}

// ---------------------------------------------------------------------------
// k_graphs (slow tier)
// ---------------------------------------------------------------------------
__global__ void k_graphs(const float* __restrict__ t2v, const float* __restrict__ tSv,
                         const float* __restrict__ W4, const float* __restrict__ b4,
                         float* __restrict__ graphs) {
    int kn = blockIdx.x;
    int k = kn / N_, n = kn % N_;
    int kup = (k + 1) % K_;
    __shared__ float F[R_][V_ * V_];
    __shared__ float w4s[O_][R_];
    __shared__ float b4s[O_];
    int tid = threadIdx.x;
    for (int i = tid; i < O_ * R_; i += 256) w4s[i / R_][i % R_] = W4[(size_t)k * O_ * R_ + i];
    if (tid < O_) b4s[tid] = b4[k * O_ + tid];
    for (int idx = tid; idx < R_ * V_ * V_; idx += 256) {
        int r = idx / (V_ * V_), uv = idx % (V_ * V_);
        int u = uv / V_, v = uv % V_;
        int ks = (u < NU_) ? kup : k;
        size_t base = (((size_t)ks * N_ + n) * R_ + r) * V_;
        F[r][uv] = tanhf(tSv[base + u] - t2v[base + v]);
    }
    __syncthreads();
    float* gout = graphs + ((size_t)k * N_ + n) * O_ * (V_ * V_);
    for (int idx = tid; idx < O_ * V_ * V_; idx += 256) {
        int o = idx / (V_ * V_), uv = idx % (V_ * V_);
        float a = b4s[o];
#pragma unroll
        for (int r = 0; r < R_; ++r) a += w4s[o][r] * F[r][uv];
        gout[idx] = a;
    }
}

// ---------------------------------------------------------------------------
// k_graphs2b (fast tier): pool-from-pp + tvals (k and kup) + F + graphs, fused.
// ---------------------------------------------------------------------------
__global__ void k_graphs2b(const float* __restrict__ pp,
                           const float* __restrict__ W11, const float* __restrict__ b11,
                           const float* __restrict__ W12, const float* __restrict__ b12,
                           const float* __restrict__ W2,  const float* __restrict__ b2,
                           const float* __restrict__ W4,  const float* __restrict__ b4,
                           float* __restrict__ graphs) {
    int kn = blockIdx.x;
    int k = kn / N_, n = kn % N_;
    int kup = (k + 1) % K_;
    __shared__ float poolL[CV];        // 6.4 KB
    __shared__ float t2s[2][R_][V_];
    __shared__ float tSs[2][R_][V_];
    __shared__ float F[R_][V_ * V_];
    __shared__ float w4s[O_][R_];
    __shared__ float b4s[O_];
    int tid = threadIdx.x;
    for (int i = tid; i < O_ * R_; i += 256) w4s[i / R_][i % R_] = W4[(size_t)k * O_ * R_ + i];
    if (tid < O_) b4s[tid] = b4[k * O_ + tid];
    // pool in LDS
    const float* ppn = pp + (size_t)n * 16 * CV;
    for (int i = tid; i < CV; i += 256) {
        float s = 0.f;
#pragma unroll
        for (int tb = 0; tb < 16; ++tb) s += ppn[(size_t)tb * CV + i];
        poolL[i] = s * (1.0f / T_);
    }
    __syncthreads();
    for (int i = tid; i < 2 * R_ * V_; i += 256) {
        int ks = i / (R_ * V_);
        int rem = i - ks * (R_ * V_);
        int r = rem / V_, v = rem - r * V_;
        int kk = ks ? kup : k;
        const float* w2 = W2 + ((size_t)kk * R_ + r) * C_;
        const float* w1 = ((v < NU_) ? W11 : W12) + ((size_t)kk * R_ + r) * C_;
        float a2 = b2[kk * R_ + r];
        float a1 = (v < NU_) ? b11[kk * R_ + r] : b12[kk * R_ + r];
        for (int c = 0; c < C_; ++c) {
            float p = poolL[c * 25 + v];
            a2 += w2[c] * p;
            a1 += w1[c] * p;
        }
        t2s[ks][r][v] = a2;
        tSs[ks][r][v] = a1;
    }
    __syncthreads();
    for (int idx = tid; idx < R_ * V_ * V_; idx += 256) {
        int r = idx / (V_ * V_), uv = idx % (V_ * V_);
        int u = uv / V_, v = uv % V_;
        int ks = (u < NU_) ? 1 : 0;
        F[r][uv] = tanhf(tSs[ks][r][u] - t2s[ks][r][v]);
    }
    __syncthreads();
    float* gout = graphs + ((size_t)k * N_ + n) * O_ * (V_ * V_);
    for (int idx = tid; idx < O_ * V_ * V_; idx += 256) {
        int o = idx / (V_ * V_), uv = idx % (V_ * V_);
        float a = b4s[o];
#pragma unroll
        for (int r = 0; r < R_; ++r) a += w4s[o][r] * F[r][uv];
        gout[idx] = a;
    }
}

// ---------------------------------------------------------------------------
// k_main_fast: per (n, 4-o group) GEMM  out[t,ncol] = bias + A·H over cv'=v*64+c
//   A = xT3 fragments (global, never LDS).
//   H formed by MFMA: for chunk kc (v=kc>>1, c-half p=kc&1):
//     H[c][u] = sum_k W3bf[k,o,c] (A-frag, REGISTERS) x Gbf[k,o,u,v] (LDS B-frag)
//   one 16x16x32 MFMA per (o, c-tile, u-tile); K padded 5->32 with zeros.
// 512 thr (8 waves), M=256 N=128 K=1600, KC=32, dbuf Hs, 1 barrier/chunk.
// ---------------------------------------------------------------------------
__global__ __launch_bounds__(512, 4) void k_main_fast(
    const unsigned short* __restrict__ xT3,  // [N][16][200][16][8] bf16 bits
    const float* __restrict__ graphs,        // [K][N][O][625]
    const float* __restrict__ Adj,           // [K][625]
    const float* __restrict__ W3,            // [K][O][C]
    const float* __restrict__ b3,            // [K][O]
    float* __restrict__ out) {

    __shared__ unsigned short Hs[2][4][NB][8];     // 16 KB
    __shared__ unsigned short Gbf[OG][25][32][8];  // 51.2 KB, bf16, k/u zero-padded
    __shared__ unsigned short zeroblk[8];          // 16 B
    __shared__ float biasS[NB];

    const int tid = threadIdx.x;
    const int bid = blockIdx.x;
    const int obase = (bid & 15) * OG;
    const int n = bid >> 4;
    const int lane = tid & 63;
    const int wv_ = tid >> 6;
    const int lr = lane & 15;
    const int eg = lane >> 4;

    if (tid < 8) zeroblk[tid] = 0;

    // ---- stage Gbf: (graphs+Adj) -> bf16, B-frag layout [o][v][u(32)][k(8)] ----
    const size_t kstride = (size_t)N_ * O_ * 625;
    for (int i = tid; i < OG * 25 * 32; i += 512) {
        int o = i / 800;
        int r = i - o * 800;
        int v = r >> 5, u = r & 31;
        unsigned short g[8] = {0, 0, 0, 0, 0, 0, 0, 0};
        if (u < U_) {
            size_t gb = ((size_t)n * O_ + obase + o) * 625 + u * 25 + v;
            int av = u * 25 + v;
#pragma unroll
            for (int k = 0; k < K_; ++k)
                g[k] = f2bf(graphs[gb + k * kstride] + Adj[k * 625 + av]);
        }
        uint4 pk;
        pk.x = (unsigned)g[0] | ((unsigned)g[1] << 16);
        pk.y = (unsigned)g[2] | ((unsigned)g[3] << 16);
        pk.z = (unsigned)g[4] | ((unsigned)g[5] << 16);
        pk.w = (unsigned)g[6] | ((unsigned)g[7] << 16);
        *(uint4*)&Gbf[o][v][u][0] = pk;
    }

    // ---- persistent W3 A-frags (registers): wave -> (ho_ = o-local, hct = c-tile) ----
    const int ho_ = wv_ >> 1;           // 0..3
    const int hct = wv_ & 1;            // 0..1
    bf16x8 wA[2];
#pragma unroll
    for (int p = 0; p < 2; ++p) {
        int c = p * 32 + hct * 16 + lr;
        short h[8] = {0, 0, 0, 0, 0, 0, 0, 0};
        if (eg == 0) {
#pragma unroll
            for (int e = 0; e < K_; ++e)
                h[e] = (short)f2bf(W3[((size_t)e * O_ + obase + ho_) * C_ + c]);
        }
        wA[p] = (bf16x8){h[0], h[1], h[2], h[3], h[4], h[5], h[6], h[7]};
    }
    __syncthreads();

    // ---- bias from Gbf (b3 is zeros in practice; kept general) ----
    if (tid < NB) {
        int o = tid >> 5, u = tid & 31;
        float bv = 0.f;
        if (u < U_) {
            float s[K_] = {0.f, 0.f, 0.f, 0.f, 0.f};
            for (int v = 0; v < V_; ++v) {
                const unsigned short* gp = &Gbf[o][v][u][0];
#pragma unroll
                for (int k = 0; k < K_; ++k) s[k] += bf2f(gp[k]);
            }
#pragma unroll
            for (int k = 0; k < K_; ++k) bv += s[k] * b3[k * O_ + obase + o];
        }
        biasS[tid] = bv;
    }

    // ---- H-former via MFMA ----
    auto h_form = [&](int buf, int kc) {
        const int v = kc >> 1, p = kc & 1;
#pragma unroll
        for (int ut = 0; ut < 2; ++ut) {
            const unsigned short* baddr = (eg == 0) ? &Gbf[ho_][v][ut * 16 + lr][0]
                                                    : &zeroblk[0];
            bf16x8 bg = *(const bf16x8*)baddr;
            f32x4 d = {0.f, 0.f, 0.f, 0.f};
            d = __builtin_amdgcn_mfma_f32_16x16x32_bf16(wA[p], bg, d, 0, 0, 0);
            // D: col = lr = u-in-tile; row = eg*4+r2 = c-in-tile
            int ncol = ho_ * 32 + ut * 16 + lr;
            int slot = hct * 2 + (eg >> 1);
            uint2 w;
            w.x = pk2(d[0], d[1]);
            w.y = pk2(d[2], d[3]);
            *(uint2*)&Hs[buf][slot][ncol][(eg & 1) * 4] = w;
        }
    };

    // ---- main MFMA wave grid ----
    const int wm = wv_ >> 1;            // 0..3 -> t-base wm*64
    const int wn = wv_ & 1;             // 0..1 -> ncol-base wn*64

    f32x4 acc[4][4];
#pragma unroll
    for (int mt = 0; mt < 4; ++mt)
#pragma unroll
        for (int nt = 0; nt < 4; ++nt) acc[mt][nt] = (f32x4){0.f, 0.f, 0.f, 0.f};

    h_form(0, 0);
    __syncthreads();

    const unsigned short* An = xT3 + (size_t)n * (T_ * CV);

    for (int kc = 0; kc < NCH; ++kc) {
        const int cur = kc & 1;
        uint4 av[4];
#pragma unroll
        for (int mt = 0; mt < 4; ++mt) {
            int tt = wm * 4 + mt;
            av[mt] = *(const uint4*)(An + ((size_t)(tt * 200 + kc * 4 + eg)) * 128 + lr * 8);
        }
        bf16x8 b[4];
#pragma unroll
        for (int nt = 0; nt < 4; ++nt)
            b[nt] = *(const bf16x8*)&Hs[cur][eg][wn * 64 + nt * 16 + lr][0];
        if (kc + 1 < NCH) h_form(cur ^ 1, kc + 1);   // H-MFMA + writes drain under main MFMA
        __builtin_amdgcn_s_setprio(1);
#pragma unroll
        for (int mt = 0; mt < 4; ++mt) {
            bf16x8 a;
            { union { uint4 u; bf16x8 h; } cvt; cvt.u = av[mt]; a = cvt.h; }
#pragma unroll
            for (int nt = 0; nt < 4; ++nt)
                acc[mt][nt] = __builtin_amdgcn_mfma_f32_16x16x32_bf16(a, b[nt], acc[mt][nt], 0, 0, 0);
        }
        __builtin_amdgcn_s_setprio(0);
        __syncthreads();
    }

    // ---- epilogue: C/D col = lane&15 (ncol), row = eg*4 + r2 (t) ----
#pragma unroll
    for (int nt = 0; nt < 4; ++nt) {
        int ncol = wn * 64 + nt * 16 + lr;
        int ol = ncol >> 5;
        int u  = ncol & 31;
        if (u < U_) {
            float bv = biasS[ncol];
            float* ob = out + ((size_t)n * O_ + obase + ol) * T_ * V_ + u;
#pragma unroll
            for (int mt = 0; mt < 4; ++mt) {
                int t0 = wm * 64 + mt * 16 + eg * 4;
#pragma unroll
                for (int r2 = 0; r2 < 4; ++r2)
                    ob[(size_t)(t0 + r2) * V_] = acc[mt][nt][r2] + bv;
            }
        }
    }
}

// ---------------------------------------------------------------------------
// k_main_slow (fallback, proven R2 path)
// ---------------------------------------------------------------------------
#define OB 4
#define TB 64
__global__ __launch_bounds__(256, 1) void k_main_slow(
    const float* __restrict__ x, const float* __restrict__ graphs,
    const float* __restrict__ A, const float* __restrict__ W3,
    const float* __restrict__ b3, float* __restrict__ out) {
    int bid = blockIdx.x;
    int tb = bid & 3;
    int ob = (bid >> 2) & 15;
    int n  = bid >> 6;
    int tid = threadIdx.x;
    int ol = tid >> 6;
    int tl = tid & 63;
    int t = tb * TB + tl;
    int o = ob * OB + ol;

    __shared__ float Gs[K_][OB][V_][28];
    __shared__ float W3s[K_][OB][C_];
    __shared__ float b3s[K_][OB];

    for (int i = tid; i < K_ * OB * V_ * V_; i += 256) {
        int k   = i / (OB * V_ * V_);
        int rem = i % (OB * V_ * V_);
        int oo  = rem / (V_ * V_);
        int uv  = rem % (V_ * V_);
        Gs[k][oo][uv / V_][uv % V_] =
            graphs[(((size_t)k * N_ + n) * O_ + ob * OB + oo) * (V_ * V_) + uv]
            + A[k * V_ * V_ + uv];
    }
    for (int i = tid; i < K_ * OB * C_; i += 256) {
        int k   = i / (OB * C_);
        int rem = i % (OB * C_);
        int oo  = rem / C_, c = rem % C_;
        W3s[k][oo][c] = W3[((size_t)k * O_ + ob * OB + oo) * C_ + c];
    }
    if (tid < K_ * OB) b3s[tid / OB][tid % OB] = b3[(tid / OB) * O_ + ob * OB + tid % OB];
    __syncthreads();

    float x2[K_][V_];
#pragma unroll
    for (int k = 0; k < K_; ++k)
#pragma unroll
        for (int v = 0; v < V_; ++v) x2[k][v] = b3s[k][ol];

    const float* xb = x + ((size_t)n * C_ * T_ + t) * V_;
    for (int c = 0; c < C_; ++c) {
        const float* p = xb + (size_t)c * T_ * V_;
        float xv[V_];
#pragma unroll
        for (int v = 0; v < V_; ++v) xv[v] = p[v];
#pragma unroll
        for (int k = 0; k < K_; ++k) {
            float w = W3s[k][ol][c];
#pragma unroll
            for (int v = 0; v < V_; ++v) x2[k][v] += w * xv[v];
        }
    }

    float acc[V_];
#pragma unroll
    for (int u = 0; u < V_; ++u) acc[u] = 0.0f;
#pragma unroll
    for (int k = 0; k < K_; ++k) {
#pragma unroll
        for (int u = 0; u < V_; ++u) {
            const float* gr = &Gs[k][ol][u][0];
            float s = 0.0f;
#pragma unroll
            for (int v = 0; v < V_; ++v) s += gr[v] * x2[k][v];
            acc[u] += s;
        }
    }
    float* po = out + (((size_t)n * O_ + o) * T_ + t) * V_;
#pragma unroll
    for (int u = 0; u < V_; ++u) po[u] = acc[u];
}

// ---------------------------------------------------------------------------
extern "C" void kernel_launch(void* const* d_in, const int* in_sizes, int n_in,
                              void* d_out, int out_size, void* d_ws, size_t ws_size,
                              hipStream_t stream) {
    const float* x   = (const float*)d_in[0];
    const float* A   = (const float*)d_in[1];
    const float* W11 = (const float*)d_in[2];
    const float* b11 = (const float*)d_in[3];
    const float* W12 = (const float*)d_in[4];
    const float* b12 = (const float*)d_in[5];
    const float* W2  = (const float*)d_in[6];
    const float* b2  = (const float*)d_in[7];
    const float* W3  = (const float*)d_in[8];
    const float* b3  = (const float*)d_in[9];
    const float* W4  = (const float*)d_in[10];
    const float* b4  = (const float*)d_in[11];

    float* out    = (float*)d_out;
    float* graphs = out + OUT_ELEMS;   // second tuple element

    const size_t xT_bytes = sizeof(unsigned short) * (size_t)N_ * T_ * CV;  // 26.2 MB
    const size_t pp_bytes = sizeof(float) * (size_t)N_ * 16 * CV;           //  3.3 MB
    const size_t hdr      = (size_t)(1 << 20);
    const bool fast = (ws_size >= hdr + xT_bytes + pp_bytes);

    const size_t poolElems = (size_t)N_ * C_ * V_;      // 51,200
    const size_t tElems    = (size_t)K_ * N_ * R_ * V_; // 32,000
    const size_t slowNeed  = (poolElems + 2 * tElems) * sizeof(float);

    float* scratch = (fast || ws_size >= slowNeed) ? (float*)d_ws : out;
    float* pool = scratch;
    float* t2v  = scratch + poolElems;
    float* tSv  = t2v + tElems;
    unsigned short* xT3 = (unsigned short*)((char*)d_ws + hdr);
    float* pp = (float*)((char*)d_ws + hdr + xT_bytes);

    if (fast) {
        k_xcast   <<<N_ * 16, 256, 0, stream>>>(x, xT3, pp);
        k_graphs2b<<<K_ * N_, 256, 0, stream>>>(pp, W11, b11, W12, b12, W2, b2, W4, b4, graphs);
        k_main_fast<<<N_ * 16, 512, 0, stream>>>(xT3, graphs, A, W3, b3, out);
    } else {
        k_pool  <<<N_ * C_, 256, 0, stream>>>(x, pool);
        k_tvals <<<K_ * N_, 256, 0, stream>>>(pool, W11, b11, W12, b12, W2, b2, t2v, tSv);
        k_graphs<<<K_ * N_, 256, 0, stream>>>(t2v, tSv, W4, b4, graphs);
        k_main_slow<<<N_ * (O_ / OB) * 4, 256, 0, stream>>>(x, graphs, A, W3, b3, out);
    }
}

// Round 9
// 116.128 us; speedup vs baseline: 2.3061x; 2.3061x over previous
//
#include <hip/hip_runtime.h>
#include <cstdint>
#include <cstddef>

#define N_  32
#define C_  64
#define T_  256
#define V_  25
#define R_  8
#define O_  64
#define K_  5
#define NU_ 17
#define U_  25
#define CV  (C_ * V_)        // 1600
#define KC  32               // K-chunk = 1 MFMA k-step
#define NCH (CV / KC)        // 50 chunks
#define OG  4                // o's per block
#define NB  (OG * 32)        // 128 ncols

#define OUT_ELEMS ((size_t)N_ * O_ * T_ * V_)   // 13,107,200

typedef __attribute__((ext_vector_type(8))) short bf16x8;
typedef __attribute__((ext_vector_type(4))) float f32x4;

// round-to-nearest-away, 2 ops
static __device__ __forceinline__ unsigned short f2bf(float f) {
    union { float f; unsigned u; } c; c.f = f;
    return (unsigned short)((c.u + 0x8000u) >> 16);
}
static __device__ __forceinline__ float bf2f(unsigned short h) {
    union { unsigned u; float f; } c; c.u = ((unsigned)h) << 16; return c.f;
}
static __device__ __forceinline__ unsigned pk2(float a, float b) {
    union { float f; unsigned u; } ca, cb; ca.f = a; cb.f = b;
    return ((ca.u + 0x8000u) >> 16) | ((cb.u + 0x8000u) & 0xFFFF0000u);
}

// ---------------------------------------------------------------------------
// k_xcast: fragment-native xT3 with cv' = v*64+c ordering:
//   xT3[n][tt(16)][s'(200)][tl(16)][ke(8)],  s' = v*8 + c/8, ke = c&7.
// Vectorized float4 input pass; flat per-c tile [c][t*25+v].
// Also per-t-block partial pool sums pp[n][tb][c*25+v].
// ---------------------------------------------------------------------------
__global__ void k_xcast(const float* __restrict__ x, unsigned short* __restrict__ xT3,
                        float* __restrict__ pp) {
    __shared__ unsigned short tile[C_][408];   // [c][t*25+v], row 816 B
    int bid = blockIdx.x;
    int n = bid >> 4, tb = bid & 15;
    int tid = threadIdx.x;
    // phase 1: 6400 float4 reads (coalesced), bf16-pack, 8B LDS writes
    const float* xb = x + (size_t)n * C_ * T_ * V_ + tb * 400;
#pragma unroll
    for (int it = 0; it < 25; ++it) {
        int i = it * 256 + tid;          // < 6400
        int c = i / 100, q = i - c * 100;
        float4 v4 = *(const float4*)(xb + (size_t)c * (T_ * V_) + q * 4);
        uint2 w;
        w.x = pk2(v4.x, v4.y);
        w.y = pk2(v4.z, v4.w);
        *(uint2*)&tile[c][q * 4] = w;
    }
    __syncthreads();
    // phase 2: write fragment tiles: dst = ((n*16+tb)*200 + s')*128 + tl*8
    unsigned short* dstb = xT3 + ((size_t)(n * 16 + tb) * 200) * 128;
    for (int i = tid; i < 200 * 16; i += 256) {
        int sp = i >> 4, tl = i & 15;
        int v = sp >> 3, c0 = (sp & 7) * 8;
        unsigned short h[8];
#pragma unroll
        for (int j = 0; j < 8; ++j) h[j] = tile[c0 + j][tl * 25 + v];
        uint4 pk;
        pk.x = (unsigned)h[0] | ((unsigned)h[1] << 16);
        pk.y = (unsigned)h[2] | ((unsigned)h[3] << 16);
        pk.z = (unsigned)h[4] | ((unsigned)h[5] << 16);
        pk.w = (unsigned)h[6] | ((unsigned)h[7] << 16);
        *(uint4*)(dstb + (size_t)sp * 128 + tl * 8) = pk;
    }
    // phase 3: partial pool
    float* ppd = pp + ((size_t)n * 16 + tb) * CV;
    for (int e = tid; e < CV; e += 256) {
        int c = e / 25, v = e - c * 25;
        float s = 0.f;
#pragma unroll
        for (int t = 0; t < 16; ++t) s += bf2f(tile[c][t * 25 + v]);
        ppd[e] = s;
    }
}

// classic pool (slow tier)
__global__ void k_pool(const float* __restrict__ x, float* __restrict__ pool) {
    int nc = blockIdx.x;
    int t  = threadIdx.x;
    const float* px = x + ((size_t)nc * T_ + t) * V_;
    float acc[V_];
#pragma unroll
    for (int v = 0; v < V_; ++v) acc[v] = px[v];
#pragma unroll
    for (int off = 32; off > 0; off >>= 1) {
#pragma unroll
        for (int v = 0; v < V_; ++v) acc[v] += __shfl_down(acc[v], off, 64);
    }
    __shared__ float sm[4][V_];
    int wave = t >> 6, lane = t & 63;
    if (lane == 0) {
#pragma unroll
        for (int v = 0; v < V_; ++v) sm[wave][v] = acc[v];
    }
    __syncthreads();
    if (t < V_) {
        float s = sm[0][t] + sm[1][t] + sm[2][t] + sm[3][t];
        pool[(size_t)nc * V_ + t] = s * (1.0f / T_);
    }
}

// ---------------------------------------------------------------------------
// k_tvals (slow tier only)
// ---------------------------------------------------------------------------
__global__ void k_tvals(const float* __restrict__ pool,
                        const float* __restrict__ W11, const float* __restrict__ b11,
                        const float* __restrict__ W12, const float* __restrict__ b12,
                        const float* __restrict__ W2,  const float* __restrict__ b2,
                        float* __restrict__ t2o, float* __restrict__ tSo) {
    int kn = blockIdx.x;
    int k = kn / N_, n = kn % N_;
    int tid = threadIdx.x;
    int r = tid >> 5, v = tid & 31;
    if (v >= V_) return;
    const float* pp = pool + (size_t)n * C_ * V_ + v;
    const float* w2 = W2 + ((size_t)k * R_ + r) * C_;
    const float* w1 = ((v < NU_) ? W11 : W12) + ((size_t)k * R_ + r) * C_;
    float a2 = b2[k * R_ + r];
    float a1 = (v < NU_) ? b11[k * R_ + r] : b12[k * R_ + r];
    for (int c = 0; c < C_; ++c) {
        float p = pp[(size_t)c * V_];
        a2 += w2[c] * p;
        a1 += w1[c] * p;
    }
    size_t idx = (((size_t)k * N_ + n) * R_ + r) * V_ + v;
    t2o[idx] = a2;
    tSo[idx] = a1;
}

// ---------------------------------------------------------------------------
// k_graphs (slow tier)
// ---------------------------------------------------------------------------
__global__ void k_graphs(const float* __restrict__ t2v, const float* __restrict__ tSv,
                         const float* __restrict__ W4, const float* __restrict__ b4,
                         float* __restrict__ graphs) {
    int kn = blockIdx.x;
    int k = kn / N_, n = kn % N_;
    int kup = (k + 1) % K_;
    __shared__ float F[R_][V_ * V_];
    __shared__ float w4s[O_][R_];
    __shared__ float b4s[O_];
    int tid = threadIdx.x;
    for (int i = tid; i < O_ * R_; i += 256) w4s[i / R_][i % R_] = W4[(size_t)k * O_ * R_ + i];
    if (tid < O_) b4s[tid] = b4[k * O_ + tid];
    for (int idx = tid; idx < R_ * V_ * V_; idx += 256) {
        int r = idx / (V_ * V_), uv = idx % (V_ * V_);
        int u = uv / V_, v = uv % V_;
        int ks = (u < NU_) ? kup : k;
        size_t base = (((size_t)ks * N_ + n) * R_ + r) * V_;
        F[r][uv] = tanhf(tSv[base + u] - t2v[base + v]);
    }
    __syncthreads();
    float* gout = graphs + ((size_t)k * N_ + n) * O_ * (V_ * V_);
    for (int idx = tid; idx < O_ * V_ * V_; idx += 256) {
        int o = idx / (V_ * V_), uv = idx % (V_ * V_);
        float a = b4s[o];
#pragma unroll
        for (int r = 0; r < R_; ++r) a += w4s[o][r] * F[r][uv];
        gout[idx] = a;
    }
}

// ---------------------------------------------------------------------------
// k_graphs2b (fast tier): pool-from-pp + tvals (k and kup) + F + graphs, fused.
// 512 threads: halves the serial per-thread loop depth of the 256-thr version.
// ---------------------------------------------------------------------------
__global__ void k_graphs2b(const float* __restrict__ pp,
                           const float* __restrict__ W11, const float* __restrict__ b11,
                           const float* __restrict__ W12, const float* __restrict__ b12,
                           const float* __restrict__ W2,  const float* __restrict__ b2,
                           const float* __restrict__ W4,  const float* __restrict__ b4,
                           float* __restrict__ graphs) {
    int kn = blockIdx.x;
    int k = kn / N_, n = kn % N_;
    int kup = (k + 1) % K_;
    __shared__ float poolL[CV];        // 6.4 KB
    __shared__ float t2s[2][R_][V_];
    __shared__ float tSs[2][R_][V_];
    __shared__ float F[R_][V_ * V_];
    __shared__ float w4s[O_][R_];
    __shared__ float b4s[O_];
    int tid = threadIdx.x;
    for (int i = tid; i < O_ * R_; i += 512) w4s[i / R_][i % R_] = W4[(size_t)k * O_ * R_ + i];
    if (tid < O_) b4s[tid] = b4[k * O_ + tid];
    // pool in LDS
    const float* ppn = pp + (size_t)n * 16 * CV;
    for (int i = tid; i < CV; i += 512) {
        float s = 0.f;
#pragma unroll
        for (int tb = 0; tb < 16; ++tb) s += ppn[(size_t)tb * CV + i];
        poolL[i] = s * (1.0f / T_);
    }
    __syncthreads();
    for (int i = tid; i < 2 * R_ * V_; i += 512) {
        int ks = i / (R_ * V_);
        int rem = i - ks * (R_ * V_);
        int r = rem / V_, v = rem - r * V_;
        int kk = ks ? kup : k;
        const float* w2 = W2 + ((size_t)kk * R_ + r) * C_;
        const float* w1 = ((v < NU_) ? W11 : W12) + ((size_t)kk * R_ + r) * C_;
        float a2 = b2[kk * R_ + r];
        float a1 = (v < NU_) ? b11[kk * R_ + r] : b12[kk * R_ + r];
        for (int c = 0; c < C_; ++c) {
            float p = poolL[c * 25 + v];
            a2 += w2[c] * p;
            a1 += w1[c] * p;
        }
        t2s[ks][r][v] = a2;
        tSs[ks][r][v] = a1;
    }
    __syncthreads();
    for (int idx = tid; idx < R_ * V_ * V_; idx += 512) {
        int r = idx / (V_ * V_), uv = idx % (V_ * V_);
        int u = uv / V_, v = uv % V_;
        int ks = (u < NU_) ? 1 : 0;
        F[r][uv] = tanhf(tSs[ks][r][u] - t2s[ks][r][v]);
    }
    __syncthreads();
    float* gout = graphs + ((size_t)k * N_ + n) * O_ * (V_ * V_);
    for (int idx = tid; idx < O_ * V_ * V_; idx += 512) {
        int o = idx / (V_ * V_), uv = idx % (V_ * V_);
        float a = b4s[o];
#pragma unroll
        for (int r = 0; r < R_; ++r) a += w4s[o][r] * F[r][uv];
        gout[idx] = a;
    }
}

// ---------------------------------------------------------------------------
// k_main_fast (PROVEN R7 version): per (n, 4-o group) GEMM over cv'=v*64+c
//   out[t,ncol] = bias + A·H ; A = xT3 fragments (global, never LDS).
//   H formed per chunk in LDS by VALU: chunk kc has ONE v (= kc>>1);
//   per thread: 1 G-load (f32x4+f32) amortized over 8 h-values; W3 k-major
//   -> 10 contiguous ds_read_b128 (2 distinct addrs/wave); 40 FMA; pk2 cvt.
// 512 thr (8 waves), M=256 N=128 K=1600, KC=32, dbuf Hs, 1 barrier/chunk.
// NOTE: register file is at the 2-blocks/CU cliff (64 VGPR + 64 acc);
// do NOT add register state here.
// ---------------------------------------------------------------------------
__global__ __launch_bounds__(512, 4) void k_main_fast(
    const unsigned short* __restrict__ xT3,  // [N][16][200][16][8] bf16 bits
    const float* __restrict__ graphs,        // [K][N][O][625]
    const float* __restrict__ Adj,           // [K][625]
    const float* __restrict__ W3,            // [K][O][C]
    const float* __restrict__ b3,            // [K][O]
    float* __restrict__ out) {

    __shared__ unsigned short Hs[2][4][NB][8];   // 16 KB
    __shared__ f32x4 Gls4[OG * 625];             // 40 KB (k0..3), idx o*625+v*25+u
    __shared__ float Gls1[OG * 625];             // 10 KB (k4)
    __shared__ f32x4 W3km[K_ * OG * 16];         //  5 KB: [k][o][c], f32x4 over c
    __shared__ float biasS[NB];                  // 512 B

    const int tid = threadIdx.x;
    const int bid = blockIdx.x;
    const int obase = (bid & 15) * OG;
    const int n = bid >> 4;
    const int lane = tid & 63;
    const int wv_ = tid >> 6;

    // ---- stage Gls ----
    const size_t kstride = (size_t)N_ * O_ * 625;
    for (int i = tid; i < OG * 625; i += 512) {
        int o = i / 625, uv = i - o * 625;
        int u = uv / 25, v = uv - u * 25;
        size_t gb = ((size_t)n * O_ + obase + o) * 625 + uv;
        f32x4 g4;
        g4[0] = graphs[gb]               + Adj[uv];
        g4[1] = graphs[gb + kstride]     + Adj[625 + uv];
        g4[2] = graphs[gb + 2 * kstride] + Adj[1250 + uv];
        g4[3] = graphs[gb + 3 * kstride] + Adj[1875 + uv];
        int idx = o * 625 + v * 25 + u;
        Gls4[idx] = g4;
        Gls1[idx] = graphs[gb + 4 * kstride] + Adj[2500 + uv];
    }
    // ---- stage W3 k-major ----
    for (int i = tid; i < K_ * OG * C_; i += 512) {   // 1280 scalars
        int k = i / (OG * C_);
        int rem = i - k * (OG * C_);
        int o = rem >> 6, c = rem & 63;
        ((float*)W3km)[((k * OG + o) * C_) + c] = W3[((size_t)k * O_ + obase + o) * C_ + c];
    }
    __syncthreads();

    // ---- in-block bias ----
    if (tid < NB) {
        int o = tid >> 5, u = tid & 31;
        float bv = 0.f;
        if (u < U_) {
            f32x4 s4 = {0.f, 0.f, 0.f, 0.f};
            float s5 = 0.f;
            for (int v = 0; v < V_; ++v) {
                int idx = o * 625 + v * 25 + u;
                s4 += Gls4[idx];
                s5 += Gls1[idx];
            }
            bv = s4[0] * b3[0 * O_ + obase + o] + s4[1] * b3[1 * O_ + obase + o]
               + s4[2] * b3[2 * O_ + obase + o] + s4[3] * b3[3 * O_ + obase + o]
               + s5 * b3[4 * O_ + obase + o];
        }
        biasS[tid] = bv;
    }

    // ---- H_FORM ----
    const int sl = wv_ & 3;
    const int hncol = (wv_ >> 2) * 64 + lane;   // 0..127
    const int ho = hncol >> 5;
    const int hu = hncol & 31;
    auto h_form = [&](int buf, int kc) {
        const int v  = kc >> 1;
        const int c0 = (kc & 1) * 32 + sl * 8;
        f32x4 g = {0.f, 0.f, 0.f, 0.f};
        float g5 = 0.f;
        if (hu < U_) {
            int gi = ho * 625 + v * 25 + hu;
            g = Gls4[gi];
            g5 = Gls1[gi];
        }
        const f32x4* wb = &W3km[(ho * 16) + (c0 >> 2)];
        const int kw = OG * 16;   // f32x4 stride per k
        f32x4 w0a = wb[0],        w0b = wb[1];
        f32x4 w1a = wb[kw],       w1b = wb[kw + 1];
        f32x4 w2a = wb[2 * kw],   w2b = wb[2 * kw + 1];
        f32x4 w3a = wb[3 * kw],   w3b = wb[3 * kw + 1];
        f32x4 w4a = wb[4 * kw],   w4b = wb[4 * kw + 1];
        float h[8];
#pragma unroll
        for (int j = 0; j < 4; ++j) {
            h[j]     = w0a[j] * g[0] + w1a[j] * g[1] + w2a[j] * g[2] + w3a[j] * g[3] + w4a[j] * g5;
            h[4 + j] = w0b[j] * g[0] + w1b[j] * g[1] + w2b[j] * g[2] + w3b[j] * g[3] + w4b[j] * g5;
        }
        uint4 hv;
        hv.x = pk2(h[0], h[1]); hv.y = pk2(h[2], h[3]);
        hv.z = pk2(h[4], h[5]); hv.w = pk2(h[6], h[7]);
        *(uint4*)&Hs[buf][sl][hncol][0] = hv;
    };

    // ---- MFMA wave grid ----
    const int wm = wv_ >> 1;            // 0..3 -> t-base wm*64
    const int wn = wv_ & 1;             // 0..1 -> ncol-base wn*64
    const int lr = lane & 15;
    const int eg = lane >> 4;

    f32x4 acc[4][4];
#pragma unroll
    for (int mt = 0; mt < 4; ++mt)
#pragma unroll
        for (int nt = 0; nt < 4; ++nt) acc[mt][nt] = (f32x4){0.f, 0.f, 0.f, 0.f};

    h_form(0, 0);
    __syncthreads();

    const unsigned short* An = xT3 + (size_t)n * (T_ * CV);

    for (int kc = 0; kc < NCH; ++kc) {
        const int cur = kc & 1;
        uint4 av[4];
#pragma unroll
        for (int mt = 0; mt < 4; ++mt) {
            int tt = wm * 4 + mt;
            av[mt] = *(const uint4*)(An + ((size_t)(tt * 200 + kc * 4 + eg)) * 128 + lr * 8);
        }
        bf16x8 b[4];
#pragma unroll
        for (int nt = 0; nt < 4; ++nt)
            b[nt] = *(const bf16x8*)&Hs[cur][eg][wn * 64 + nt * 16 + lr][0];
        __builtin_amdgcn_s_setprio(1);
#pragma unroll
        for (int mt = 0; mt < 4; ++mt) {
            bf16x8 a;
            { union { uint4 u; bf16x8 h; } cvt; cvt.u = av[mt]; a = cvt.h; }
#pragma unroll
            for (int nt = 0; nt < 4; ++nt)
                acc[mt][nt] = __builtin_amdgcn_mfma_f32_16x16x32_bf16(a, b[nt], acc[mt][nt], 0, 0, 0);
        }
        __builtin_amdgcn_s_setprio(0);
        if (kc + 1 < NCH) h_form(cur ^ 1, kc + 1);
        __syncthreads();
    }

    // ---- epilogue: C/D col = lane&15 (ncol), row = eg*4 + r2 (t) ----
#pragma unroll
    for (int nt = 0; nt < 4; ++nt) {
        int ncol = wn * 64 + nt * 16 + lr;
        int ol = ncol >> 5;
        int u  = ncol & 31;
        if (u < U_) {
            float bv = biasS[ncol];
            float* ob = out + ((size_t)n * O_ + obase + ol) * T_ * V_ + u;
#pragma unroll
            for (int mt = 0; mt < 4; ++mt) {
                int t0 = wm * 64 + mt * 16 + eg * 4;
#pragma unroll
                for (int r2 = 0; r2 < 4; ++r2)
                    ob[(size_t)(t0 + r2) * V_] = acc[mt][nt][r2] + bv;
            }
        }
    }
}

// ---------------------------------------------------------------------------
// k_main_slow (fallback, proven R2 path)
// ---------------------------------------------------------------------------
#define OB 4
#define TB 64
__global__ __launch_bounds__(256, 1) void k_main_slow(
    const float* __restrict__ x, const float* __restrict__ graphs,
    const float* __restrict__ A, const float* __restrict__ W3,
    const float* __restrict__ b3, float* __restrict__ out) {
    int bid = blockIdx.x;
    int tb = bid & 3;
    int ob = (bid >> 2) & 15;
    int n  = bid >> 6;
    int tid = threadIdx.x;
    int ol = tid >> 6;
    int tl = tid & 63;
    int t = tb * TB + tl;
    int o = ob * OB + ol;

    __shared__ float Gs[K_][OB][V_][28];
    __shared__ float W3s[K_][OB][C_];
    __shared__ float b3s[K_][OB];

    for (int i = tid; i < K_ * OB * V_ * V_; i += 256) {
        int k   = i / (OB * V_ * V_);
        int rem = i % (OB * V_ * V_);
        int oo  = rem / (V_ * V_);
        int uv  = rem % (V_ * V_);
        Gs[k][oo][uv / V_][uv % V_] =
            graphs[(((size_t)k * N_ + n) * O_ + ob * OB + oo) * (V_ * V_) + uv]
            + A[k * V_ * V_ + uv];
    }
    for (int i = tid; i < K_ * OB * C_; i += 256) {
        int k   = i / (OB * C_);
        int rem = i % (OB * C_);
        int oo  = rem / C_, c = rem % C_;
        W3s[k][oo][c] = W3[((size_t)k * O_ + ob * OB + oo) * C_ + c];
    }
    if (tid < K_ * OB) b3s[tid / OB][tid % OB] = b3[(tid / OB) * O_ + ob * OB + tid % OB];
    __syncthreads();

    float x2[K_][V_];
#pragma unroll
    for (int k = 0; k < K_; ++k)
#pragma unroll
        for (int v = 0; v < V_; ++v) x2[k][v] = b3s[k][ol];

    const float* xb = x + ((size_t)n * C_ * T_ + t) * V_;
    for (int c = 0; c < C_; ++c) {
        const float* p = xb + (size_t)c * T_ * V_;
        float xv[V_];
#pragma unroll
        for (int v = 0; v < V_; ++v) xv[v] = p[v];
#pragma unroll
        for (int k = 0; k < K_; ++k) {
            float w = W3s[k][ol][c];
#pragma unroll
            for (int v = 0; v < V_; ++v) x2[k][v] += w * xv[v];
        }
    }

    float acc[V_];
#pragma unroll
    for (int u = 0; u < V_; ++u) acc[u] = 0.0f;
#pragma unroll
    for (int k = 0; k < K_; ++k) {
#pragma unroll
        for (int u = 0; u < V_; ++u) {
            const float* gr = &Gs[k][ol][u][0];
            float s = 0.0f;
#pragma unroll
            for (int v = 0; v < V_; ++v) s += gr[v] * x2[k][v];
            acc[u] += s;
        }
    }
    float* po = out + (((size_t)n * O_ + o) * T_ + t) * V_;
#pragma unroll
    for (int u = 0; u < V_; ++u) po[u] = acc[u];
}

// ---------------------------------------------------------------------------
extern "C" void kernel_launch(void* const* d_in, const int* in_sizes, int n_in,
                              void* d_out, int out_size, void* d_ws, size_t ws_size,
                              hipStream_t stream) {
    const float* x   = (const float*)d_in[0];
    const float* A   = (const float*)d_in[1];
    const float* W11 = (const float*)d_in[2];
    const float* b11 = (const float*)d_in[3];
    const float* W12 = (const float*)d_in[4];
    const float* b12 = (const float*)d_in[5];
    const float* W2  = (const float*)d_in[6];
    const float* b2  = (const float*)d_in[7];
    const float* W3  = (const float*)d_in[8];
    const float* b3  = (const float*)d_in[9];
    const float* W4  = (const float*)d_in[10];
    const float* b4  = (const float*)d_in[11];

    float* out    = (float*)d_out;
    float* graphs = out + OUT_ELEMS;   // second tuple element

    const size_t xT_bytes = sizeof(unsigned short) * (size_t)N_ * T_ * CV;  // 26.2 MB
    const size_t pp_bytes = sizeof(float) * (size_t)N_ * 16 * CV;           //  3.3 MB
    const size_t hdr      = (size_t)(1 << 20);
    const bool fast = (ws_size >= hdr + xT_bytes + pp_bytes);

    const size_t poolElems = (size_t)N_ * C_ * V_;      // 51,200
    const size_t tElems    = (size_t)K_ * N_ * R_ * V_; // 32,000
    const size_t slowNeed  = (poolElems + 2 * tElems) * sizeof(float);

    float* scratch = (fast || ws_size >= slowNeed) ? (float*)d_ws : out;
    float* pool = scratch;
    float* t2v  = scratch + poolElems;
    float* tSv  = t2v + tElems;
    unsigned short* xT3 = (unsigned short*)((char*)d_ws + hdr);
    float* pp = (float*)((char*)d_ws + hdr + xT_bytes);

    if (fast) {
        k_xcast   <<<N_ * 16, 256, 0, stream>>>(x, xT3, pp);
        k_graphs2b<<<K_ * N_, 512, 0, stream>>>(pp, W11, b11, W12, b12, W2, b2, W4, b4, graphs);
        k_main_fast<<<N_ * 16, 512, 0, stream>>>(xT3, graphs, A, W3, b3, out);
    } else {
        k_pool  <<<N_ * C_, 256, 0, stream>>>(x, pool);
        k_tvals <<<K_ * N_, 256, 0, stream>>>(pool, W11, b11, W12, b12, W2, b2, t2v, tSv);
        k_graphs<<<K_ * N_, 256, 0, stream>>>(t2v, tSv, W4, b4, graphs);
        k_main_slow<<<N_ * (O_ / OB) * 4, 256, 0, stream>>>(x, graphs, A, W3, b3, out);
    }
}